// Round 14
// baseline (809.442 us; speedup 1.0000x reference)
//
#include <hip/hip_runtime.h>
#include <math.h>

#define N_NODES 100000
#define N_EDGES 1200000
#define N_GRAPHS 256
#define CH 64
#define NC (N_NODES * CH)
#define EPS 1e-5f

#define SCAN_NB 98            // ceil((N_NODES+1)/1024)
#define ZSTRN 72              // f16 stride for node-GEMM A tile
#define GTILES ((N_NODES + 63) / 64)
#define EA_BLOCKS 2048
#define NW (EA_BLOCKS * 4)    // wave partial count
#define POOL_BLOCKS 256

typedef _Float16 half8 __attribute__((ext_vector_type(8)));
typedef _Float16 half2v __attribute__((ext_vector_type(2)));
typedef float floatx4 __attribute__((ext_vector_type(4)));

__device__ __forceinline__ int lbound(const int* __restrict__ a, int n, int v) {
    int lo = 0, hi = n;
    while (lo < hi) {
        int mid = (lo + hi) >> 1;
        if (a[mid] < v) lo = mid + 1; else hi = mid;
    }
    return lo;
}

__device__ __forceinline__ float edge_m(float f, float s) {
    float sig = __builtin_amdgcn_rcpf(1.0f + __expf(-f));
    float sp  = fmaxf(s, 0.0f) + __logf(1.0f + __expf(-fabsf(s)));
    return sig * sp;
}

// ---------------- embed + BN0 stats fused ----------------
__global__ void embed_stats_kernel(const float* __restrict__ x,
                                   const float* __restrict__ W,   // [12,64]
                                   const float* __restrict__ b,   // [64]
                                   float* __restrict__ out,       // [N,64]
                                   float* __restrict__ stats) {   // [128] pre-zeroed
    int c = threadIdx.x & 63;
    int sub = threadIdx.x >> 6;
    float s = 0.f, q = 0.f;
    for (int r = blockIdx.x * 4 + sub; r < N_NODES; r += gridDim.x * 4) {
        const float* xr = x + r * 12;
        float acc = b[c];
#pragma unroll
        for (int k = 0; k < 12; ++k)
            acc = fmaf(xr[k], W[k * CH + c], acc);
        out[(size_t)r * CH + c] = acc;
        s += acc;
        q = fmaf(acc, acc, q);
    }
    __shared__ float ls[4][64];
    __shared__ float lq[4][64];
    ls[sub][c] = s;
    lq[sub][c] = q;
    __syncthreads();
    if (sub == 0) {
        s = ls[0][c] + ls[1][c] + ls[2][c] + ls[3][c];
        q = lq[0][c] + lq[1][c] + lq[2][c] + lq[3][c];
        atomicAdd(&stats[c], s);
        atomicAdd(&stats[64 + c], q);
    }
}

// ---------------- counting sort of edges by dst ----------------
__global__ void hist_kernel(const int* __restrict__ ei,
                            int* __restrict__ rowptr) { // [N+1] pre-zeroed
    int e = blockIdx.x * blockDim.x + threadIdx.x;
    if (e < N_EDGES) atomicAdd(&rowptr[ei[N_EDGES + e] + 1], 1);
}

__global__ void scanA_kernel(int* __restrict__ a, int* __restrict__ btot) {
    __shared__ int wsum[16];
    int t = threadIdx.x, lane = t & 63, w = t >> 6;
    int i = blockIdx.x * 1024 + t;
    int v = (i <= N_NODES) ? a[i] : 0;
    int s = v;
#pragma unroll
    for (int d = 1; d < 64; d <<= 1) {
        int o = __shfl_up(s, d);
        if (lane >= d) s += o;
    }
    if (lane == 63) wsum[w] = s;
    __syncthreads();
    if (w == 0) {
        int ws2 = (lane < 16) ? wsum[lane] : 0;
#pragma unroll
        for (int d = 1; d < 16; d <<= 1) {
            int o = __shfl_up(ws2, d);
            if (lane >= d) ws2 += o;
        }
        if (lane < 16) wsum[lane] = ws2;
    }
    __syncthreads();
    int off = (w > 0) ? wsum[w - 1] : 0;
    if (i <= N_NODES) a[i] = s + off;
    if (t == 0) btot[blockIdx.x] = wsum[15];
}

__global__ void scanB_kernel(int* __restrict__ btot) { // 1 block, 64 threads
    int lane = threadIdx.x;
    int carry = 0;
    for (int base = 0; base < SCAN_NB; base += 64) {
        int i = base + lane;
        int v = (i < SCAN_NB) ? btot[i] : 0;
        int s = v;
#pragma unroll
        for (int d = 1; d < 64; d <<= 1) {
            int o = __shfl_up(s, d);
            if (lane >= d) s += o;
        }
        if (i < SCAN_NB) btot[i] = s + carry;
        carry += __shfl(s, 63);
    }
}

__global__ void scanC_kernel(int* __restrict__ a, const int* __restrict__ btot,
                             int* __restrict__ cursor) {
    int i = blockIdx.x * 1024 + threadIdx.x;
    int off = (blockIdx.x > 0) ? btot[blockIdx.x - 1] : 0;
    if (i <= N_NODES) {
        int val = a[i] + off;
        a[i] = val;
        if (i < N_NODES) cursor[i] = val;
    }
}

// 4B random write per edge (halves XCD write-bounce vs 8B sef write)
__global__ void scatter_perm_kernel(const int* __restrict__ ei,
                                    int* __restrict__ cursor,
                                    int* __restrict__ perm) {
    int e = blockIdx.x * blockDim.x + threadIdx.x;
    if (e >= N_EDGES) return;
    int d = ei[N_EDGES + e];
    int pos = atomicAdd(&cursor[d], 1);
    perm[pos] = e;
}

// sequential sef build: coalesced 8B writes, L3-resident 4B gathers
__global__ void build_sef_kernel(const int* __restrict__ perm,
                                 const int* __restrict__ ei,
                                 const float* __restrict__ ea,
                                 int2* __restrict__ sef) {
    int p = blockIdx.x * blockDim.x + threadIdx.x;
    if (p >= N_EDGES) return;
    int e = perm[p];
    sef[p] = make_int2(ei[e], __float_as_int(ea[e]));
}

// ---------- weight prep: pqrs layout [P(64) | R(64) | QS interleaved(128)] --
__global__ void prep_weights_kernel(const float* __restrict__ Wf,  // [129,64]
                                    const float* __restrict__ Ws,  // [129,64]
                                    const float* __restrict__ bf,
                                    const float* __restrict__ bs,
                                    _Float16* __restrict__ WT2,    // [256,64]
                                    float* __restrict__ w128,      // [128]
                                    float* __restrict__ bias) {    // [128]
    int idx = blockIdx.x * blockDim.x + threadIdx.x;  // 16384
    if (idx < 256 * 64) {
        int cc = idx >> 6;
        int k = idx & 63;
        float v;
        if (cc < 64)       v = Wf[k * 64 + cc];
        else if (cc < 128) v = Ws[k * 64 + (cc - 64)];
        else {
            int j = cc - 128, ch = j >> 1;
            v = (j & 1) ? Ws[(64 + k) * 64 + ch] : Wf[(64 + k) * 64 + ch];
        }
        WT2[idx] = (_Float16)v;
    }
    if (idx < 128) {
        w128[idx] = (idx < 64) ? Wf[128 * 64 + idx] : Ws[128 * 64 + (idx - 64)];
        bias[idx] = (idx < 64) ? bf[idx] : bs[idx - 64];
    }
}

// ------ node GEMM with fused BN(+res,+relu): h = relu(BN(ain)+res) ---------
template <bool RES>
__global__ __launch_bounds__(256)
void node_gemm_kernel(const float* __restrict__ ain,    // [N,64]
                      const float* __restrict__ res,    // [N,64] or null
                      const float* __restrict__ stats,  // [128]
                      const float* __restrict__ gamma,
                      const float* __restrict__ beta,
                      const _Float16* __restrict__ WT2, // [256,64]
                      float* __restrict__ hout,         // [N,64]
                      _Float16* __restrict__ pqrs) {    // [N,256]
    __shared__ __align__(16) _Float16 As[64 * ZSTRN];
    __shared__ __align__(16) float ab[128];
    const int t = threadIdx.x;
    const int lane = t & 63;
    const int w = t >> 6;
    const int l15 = lane & 15;
    const int quad = lane >> 4;

    if (t < 64) {
        float mean = stats[t] * (1.0f / (float)N_NODES);
        float var  = stats[64 + t] * (1.0f / (float)N_NODES) - mean * mean;
        float inv  = rsqrtf(var + EPS);
        float A = gamma[t] * inv;
        ab[t] = A;
        ab[64 + t] = beta[t] - mean * A;
    }

    half8 bfr[4][2];
#pragma unroll
    for (int tt = 0; tt < 4; ++tt)
#pragma unroll
        for (int ks = 0; ks < 2; ++ks)
            bfr[tt][ks] = *(const half8*)(WT2 + (w * 64 + tt * 16 + l15) * 64 + ks * 32 + quad * 8);
    __syncthreads();

    const int base = blockIdx.x * 64;
    {
        const int e = t >> 2, q = t & 3;
        const int row = base + e;
        const bool valid = (row < N_NODES);
        const int crow = valid ? row : (N_NODES - 1);
        const float* ap = ain + (size_t)crow * CH + q * 16;
        const float* rp = res + (size_t)crow * CH + q * 16;  // unused if !RES
        float vv[16];
#pragma unroll
        for (int i = 0; i < 4; ++i) {
            float4 a4 = *(const float4*)(ap + i * 4);
            float4 A4 = *(const float4*)(ab + q * 16 + i * 4);
            float4 B4 = *(const float4*)(ab + 64 + q * 16 + i * 4);
            float rx = 0.f, ry = 0.f, rz = 0.f, rw = 0.f;
            if (RES) {
                float4 r4 = *(const float4*)(rp + i * 4);
                rx = r4.x; ry = r4.y; rz = r4.z; rw = r4.w;
            }
            vv[i * 4 + 0] = fmaxf(fmaf(a4.x, A4.x, B4.x) + rx, 0.0f);
            vv[i * 4 + 1] = fmaxf(fmaf(a4.y, A4.y, B4.y) + ry, 0.0f);
            vv[i * 4 + 2] = fmaxf(fmaf(a4.z, A4.z, B4.z) + rz, 0.0f);
            vv[i * 4 + 3] = fmaxf(fmaf(a4.w, A4.w, B4.w) + rw, 0.0f);
        }
        if (valid) {
            float* hp = hout + (size_t)row * CH + q * 16;
#pragma unroll
            for (int i = 0; i < 4; ++i)
                *(float4*)(hp + i * 4) = make_float4(vv[i * 4], vv[i * 4 + 1], vv[i * 4 + 2], vv[i * 4 + 3]);
        }
        half8 o;
#pragma unroll
        for (int j = 0; j < 8; ++j) o[j] = (_Float16)vv[j];
        *(half8*)(As + e * ZSTRN + q * 16) = o;
#pragma unroll
        for (int j = 0; j < 8; ++j) o[j] = (_Float16)vv[8 + j];
        *(half8*)(As + e * ZSTRN + q * 16 + 8) = o;
    }
    __syncthreads();

    floatx4 acc[4][4];   // [rt][tt]
#pragma unroll
    for (int rt = 0; rt < 4; ++rt)
#pragma unroll
        for (int tt = 0; tt < 4; ++tt)
#pragma unroll
            for (int r = 0; r < 4; ++r) acc[rt][tt][r] = 0.f;

#pragma unroll
    for (int ks = 0; ks < 2; ++ks) {
#pragma unroll
        for (int rt = 0; rt < 4; ++rt) {
            half8 a = *(const half8*)(As + (rt * 16 + l15) * ZSTRN + ks * 32 + quad * 8);
#pragma unroll
            for (int tt = 0; tt < 4; ++tt)
                acc[rt][tt] = __builtin_amdgcn_mfma_f32_16x16x32_f16(a, bfr[tt][ks], acc[rt][tt], 0, 0, 0);
        }
    }

#pragma unroll
    for (int rt = 0; rt < 4; ++rt) {
#pragma unroll
        for (int r = 0; r < 4; ++r) {
            int row = base + rt * 16 + quad * 4 + r;
            if (row < N_NODES) {
#pragma unroll
                for (int tt = 0; tt < 4; ++tt)
                    pqrs[(size_t)row * 256 + w * 64 + tt * 16 + l15] = (_Float16)acc[rt][tt][r];
            }
        }
    }
}

// --- fused edge compute + aggregation: node walkers, unroll-4 gathers -------
__global__ __launch_bounds__(256)
void edge_agg_kernel(const _Float16* __restrict__ pqrs,  // [N,256] P|R|QS
                     const int2* __restrict__ sef,       // [E] {src, ea}
                     const int* __restrict__ rowptr,     // [N+1]
                     const float* __restrict__ w128,     // [128]
                     const float* __restrict__ bias,     // [128]
                     float* __restrict__ agg,            // [N,64]
                     float* __restrict__ wpart) {        // [NW,128]
    const int lane = threadIdx.x & 63;
    const int gw = (blockIdx.x * blockDim.x + threadIdx.x) >> 6;
    const int nw = NW;
    const float wfc = w128[lane], wsc = w128[64 + lane];
    const float bfc = bias[lane], bsc = bias[64 + lane];
    const char* qsbase = (const char*)pqrs + 256 + (size_t)lane * 4;

    const int e0t = (int)((long)gw * N_EDGES / nw);
    const int e1t = (int)((long)(gw + 1) * N_EDGES / nw);
    int n0 = lbound(rowptr, N_NODES + 1, e0t);
    int n1 = (gw == nw - 1) ? N_NODES : lbound(rowptr, N_NODES + 1, e1t);

    float ssum = 0.f, sqsum = 0.f;
    for (int n = n0; n < n1; ++n) {
        const int rs = rowptr[n], re = rowptr[n + 1];
        const _Float16* prow = pqrs + (size_t)n * 256;
        const float fb = (float)prow[lane] + bfc;
        const float sb = (float)prow[64 + lane] + bsc;
        float acc0 = 0.f, acc1 = 0.f, acc2 = 0.f, acc3 = 0.f;
        int e = rs;
        for (; e + 4 <= re; e += 4) {
            int2 s0 = sef[e];
            int2 s1 = sef[e + 1];
            int2 s2 = sef[e + 2];
            int2 s3 = sef[e + 3];
            half2v q0 = *(const half2v*)(qsbase + ((size_t)s0.x << 9));
            half2v q1 = *(const half2v*)(qsbase + ((size_t)s1.x << 9));
            half2v q2 = *(const half2v*)(qsbase + ((size_t)s2.x << 9));
            half2v q3 = *(const half2v*)(qsbase + ((size_t)s3.x << 9));
            float ea0 = __int_as_float(s0.y), ea1 = __int_as_float(s1.y);
            float ea2 = __int_as_float(s2.y), ea3 = __int_as_float(s3.y);
            acc0 += edge_m(fmaf(ea0, wfc, fb + (float)q0[0]), fmaf(ea0, wsc, sb + (float)q0[1]));
            acc1 += edge_m(fmaf(ea1, wfc, fb + (float)q1[0]), fmaf(ea1, wsc, sb + (float)q1[1]));
            acc2 += edge_m(fmaf(ea2, wfc, fb + (float)q2[0]), fmaf(ea2, wsc, sb + (float)q2[1]));
            acc3 += edge_m(fmaf(ea3, wfc, fb + (float)q3[0]), fmaf(ea3, wsc, sb + (float)q3[1]));
        }
        for (; e < re; ++e) {
            int2 s0 = sef[e];
            half2v q0 = *(const half2v*)(qsbase + ((size_t)s0.x << 9));
            float ea0 = __int_as_float(s0.y);
            acc0 += edge_m(fmaf(ea0, wfc, fb + (float)q0[0]), fmaf(ea0, wsc, sb + (float)q0[1]));
        }
        float acc = (acc0 + acc1) + (acc2 + acc3);
        agg[(size_t)n * CH + lane] = acc;
        ssum += acc;
        sqsum = fmaf(acc, acc, sqsum);
    }
    wpart[(size_t)gw * 128 + lane] = ssum;
    wpart[(size_t)gw * 128 + 64 + lane] = sqsum;
}

// ---- reduce wave partials -> stats[128] (128 blocks x 64 rows each) -------
__global__ __launch_bounds__(256)
void reduce_stats_kernel(const float* __restrict__ wpart, // [NW,128]
                         float* __restrict__ stats) {     // [128] pre-zeroed
    __shared__ float red[2][128];
    const int col = threadIdx.x & 127;
    const int rg = threadIdx.x >> 7;   // 0..1
    const int rows = NW / 128;         // 64
    const int r0 = blockIdx.x * rows;
    float s = 0.f;
    for (int r = r0 + rg; r < r0 + rows; r += 2)
        s += wpart[(size_t)r * 128 + col];
    red[rg][col] = s;
    __syncthreads();
    if (rg == 0) atomicAdd(&stats[col], red[0][col] + red[1][col]);
}

// ---------- pool with fused final BN(+residual): mean over graphs ----------
__global__ __launch_bounds__(256)
void pool_bn_kernel(const float* __restrict__ ain,   // agg3 [N,64]
                    const float* __restrict__ res,   // h2 [N,64]
                    const float* __restrict__ stats, // [128]
                    const float* __restrict__ gamma,
                    const float* __restrict__ beta,
                    const int* __restrict__ batch,
                    float* __restrict__ pooled,      // [G,64] pre-zeroed
                    float* __restrict__ counts) {    // [G]   pre-zeroed
    __shared__ float ab[128];
    if (threadIdx.x < 64) {
        int t = threadIdx.x;
        float mean = stats[t] * (1.0f / (float)N_NODES);
        float var  = stats[64 + t] * (1.0f / (float)N_NODES) - mean * mean;
        float inv  = rsqrtf(var + EPS);
        float A = gamma[t] * inv;
        ab[t] = A;
        ab[64 + t] = beta[t] - mean * A;
    }
    __syncthreads();

    const int c = threadIdx.x & 63;
    const float A = ab[c], B = ab[64 + c];
    const int walker = blockIdx.x * 4 + (threadIdx.x >> 6);
    const int nwalk = POOL_BLOCKS * 4;
    const int chunk = (N_NODES + nwalk - 1) / nwalk;
    int r0 = walker * chunk;
    int r1 = min(N_NODES, r0 + chunk);
    if (r0 >= r1) return;

    int cur = batch[r0];
    float acc = 0.0f;
    int runlen = 0;
    for (int r = r0; r < r1; ++r) {
        int b = batch[r];
        if (b != cur) {
            atomicAdd(&pooled[cur * CH + c], acc);
            if (c == 0) atomicAdd(&counts[cur], (float)runlen);
            acc = 0.0f;
            runlen = 0;
            cur = b;
        }
        size_t idx = (size_t)r * CH + c;
        acc += fmaf(ain[idx], A, B) + res[idx];
        ++runlen;
    }
    atomicAdd(&pooled[cur * CH + c], acc);
    if (c == 0) atomicAdd(&counts[cur], (float)runlen);
}

// ---------------- head ----------------
__global__ void head_kernel(const float* __restrict__ pooled,
                            const float* __restrict__ counts,
                            const float* __restrict__ W1,
                            const float* __restrict__ b1,
                            const float* __restrict__ W2,
                            const float* __restrict__ b2,
                            float* __restrict__ out) {
    int gph = blockIdx.x;
    int t = threadIdx.x;  // 64
    __shared__ float p[64];
    __shared__ float h1[32];
    float cnt = fmaxf(counts[gph], 1.0f);
    p[t] = pooled[gph * CH + t] / cnt;
    __syncthreads();
    if (t < 32) {
        float acc = b1[t];
#pragma unroll
        for (int c = 0; c < 64; ++c)
            acc = fmaf(p[c], W1[c * 32 + t], acc);
        h1[t] = fmaxf(acc, 0.0f);
    }
    __syncthreads();
    if (t == 0) {
        float acc = b2[0];
#pragma unroll
        for (int j = 0; j < 32; ++j)
            acc = fmaf(h1[j], W2[j], acc);
        out[gph] = acc;
    }
}

extern "C" void kernel_launch(void* const* d_in, const int* in_sizes, int n_in,
                              void* d_out, int out_size, void* d_ws, size_t ws_size,
                              hipStream_t stream) {
    const float* x     = (const float*)d_in[0];
    const int*   ei    = (const int*)d_in[1];
    const float* ea    = (const float*)d_in[2];
    const int*   batch = (const int*)d_in[3];
    const float* W_in  = (const float*)d_in[4];
    const float* b_in  = (const float*)d_in[5];
    const float* g0    = (const float*)d_in[6];
    const float* beta0 = (const float*)d_in[7];

    const float* Wf[3] = {(const float*)d_in[8],  (const float*)d_in[14], (const float*)d_in[20]};
    const float* bfv[3]= {(const float*)d_in[9],  (const float*)d_in[15], (const float*)d_in[21]};
    const float* Wsv[3]= {(const float*)d_in[10], (const float*)d_in[16], (const float*)d_in[22]};
    const float* bsv[3]= {(const float*)d_in[11], (const float*)d_in[17], (const float*)d_in[23]};
    const float* gm[3] = {(const float*)d_in[12], (const float*)d_in[18], (const float*)d_in[24]};
    const float* bb[3] = {(const float*)d_in[13], (const float*)d_in[19], (const float*)d_in[25]};

    const float* W1 = (const float*)d_in[26];
    const float* b1 = (const float*)d_in[27];
    const float* W2 = (const float*)d_in[28];
    const float* b2 = (const float*)d_in[29];

    float* out = (float*)d_out;

    // ---- workspace layout (byte-based) ----
    char* base = (char*)d_ws;
    size_t off = 0;
    float* bufA = (float*)(base + off);       off += (size_t)NC * 4;  // E0 / h1
    float* bufB = (float*)(base + off);       off += (size_t)NC * 4;  // h0 / h2
    float* AGG  = (float*)(base + off);       off += (size_t)NC * 4;
    _Float16* WT2 = (_Float16*)(base + off);  off += 3 * 256 * 64 * 2;
    float* w128   = (float*)(base + off);     off += 3 * 128 * 4;
    float* biasL  = (float*)(base + off);     off += 3 * 128 * 4;
    int* cursor   = (int*)(base + off);       off += (size_t)N_NODES * 4;
    int* perm     = (int*)(base + off);       off += (size_t)N_EDGES * 4;
    int2* sef     = (int2*)(base + off);      off += (size_t)N_EDGES * 8;
    _Float16* pqrs = (_Float16*)(base + off); off += (size_t)N_NODES * 256 * 2; // 51.2MB
    float* wpart  = (float*)(base + off);     off += (size_t)NW * 128 * 4;      // 4MB
    // ---- contiguous zero-region ----
    char* zbase   = base + off;
    int* rowptr   = (int*)(base + off);       off += (size_t)(N_NODES + 1) * 4;
    int* btot     = (int*)(base + off);       off += SCAN_NB * 4;
    float* stats4 = (float*)(base + off);     off += 4 * 128 * 4;   // stats l=0..3
    float* pooled = (float*)(base + off);     off += (size_t)N_GRAPHS * CH * 4;
    float* counts = (float*)(base + off);     off += (size_t)N_GRAPHS * 4;
    size_t zbytes = (size_t)(base + off - zbase);

    const int edgeBlocks = (N_EDGES + 255) / 256;

    hipMemsetAsync(zbase, 0, zbytes, stream);

    // ---- sort edges by dst: hist + 3-phase scan + perm scatter + sef build --
    hist_kernel<<<edgeBlocks, 256, 0, stream>>>(ei, rowptr);
    scanA_kernel<<<SCAN_NB, 1024, 0, stream>>>(rowptr, btot);
    scanB_kernel<<<1, 64, 0, stream>>>(btot);
    scanC_kernel<<<SCAN_NB, 1024, 0, stream>>>(rowptr, btot, cursor);
    scatter_perm_kernel<<<edgeBlocks, 256, 0, stream>>>(ei, cursor, perm);
    build_sef_kernel<<<edgeBlocks, 256, 0, stream>>>(perm, ei, ea, sef);

    // ---- prep f16 weights (P|R|QS-interleaved column order) ----
    for (int l = 0; l < 3; ++l)
        prep_weights_kernel<<<64, 256, 0, stream>>>(Wf[l], Wsv[l], bfv[l], bsv[l],
                                                    WT2 + l * 256 * 64, w128 + l * 128,
                                                    biasL + l * 128);

    // ---- embed + BN0 stats ----
    embed_stats_kernel<<<512, 256, 0, stream>>>(x, W_in, b_in, bufA, stats4);

    // ---- layer pipeline ----
    node_gemm_kernel<false><<<GTILES, 256, 0, stream>>>(
        bufA, nullptr, stats4, g0, beta0, WT2 + 0 * 256 * 64, bufB, pqrs);
    edge_agg_kernel<<<EA_BLOCKS, 256, 0, stream>>>(
        pqrs, sef, rowptr, w128 + 0 * 128, biasL + 0 * 128, AGG, wpart);
    reduce_stats_kernel<<<128, 256, 0, stream>>>(wpart, stats4 + 128);

    node_gemm_kernel<true><<<GTILES, 256, 0, stream>>>(
        AGG, bufB, stats4 + 128, gm[0], bb[0], WT2 + 1 * 256 * 64, bufA, pqrs);
    edge_agg_kernel<<<EA_BLOCKS, 256, 0, stream>>>(
        pqrs, sef, rowptr, w128 + 1 * 128, biasL + 1 * 128, AGG, wpart);
    reduce_stats_kernel<<<128, 256, 0, stream>>>(wpart, stats4 + 256);

    node_gemm_kernel<true><<<GTILES, 256, 0, stream>>>(
        AGG, bufA, stats4 + 256, gm[1], bb[1], WT2 + 2 * 256 * 64, bufB, pqrs);
    edge_agg_kernel<<<EA_BLOCKS, 256, 0, stream>>>(
        pqrs, sef, rowptr, w128 + 2 * 128, biasL + 2 * 128, AGG, wpart);
    reduce_stats_kernel<<<128, 256, 0, stream>>>(wpart, stats4 + 384);

    // pool with fused BN3 + residual h2
    pool_bn_kernel<<<POOL_BLOCKS, 256, 0, stream>>>(
        AGG, bufB, stats4 + 384, gm[2], bb[2], batch, pooled, counts);
    head_kernel<<<N_GRAPHS, 64, 0, stream>>>(pooled, counts, W1, b1, W2, b2, out);
}

// Round 15
// 761.568 us; speedup vs baseline: 1.0629x; 1.0629x over previous
//
#include <hip/hip_runtime.h>
#include <math.h>

#define N_NODES 100000
#define N_EDGES 1200000
#define N_GRAPHS 256
#define CH 64
#define NC (N_NODES * CH)
#define EPS 1e-5f

#define SCAN_NB 98            // ceil((N_NODES+1)/1024)
#define ZSTRN 72              // f16 stride for node-GEMM A tile
#define GTILES ((N_NODES + 63) / 64)
#define EA_BLOCKS 2048
#define NW (EA_BLOCKS * 4)    // wave partial count
#define POOL_BLOCKS 256

typedef _Float16 half8 __attribute__((ext_vector_type(8)));
typedef _Float16 half2v __attribute__((ext_vector_type(2)));
typedef float floatx4 __attribute__((ext_vector_type(4)));

__device__ __forceinline__ int lbound(const int* __restrict__ a, int n, int v) {
    int lo = 0, hi = n;
    while (lo < hi) {
        int mid = (lo + hi) >> 1;
        if (a[mid] < v) lo = mid + 1; else hi = mid;
    }
    return lo;
}

__device__ __forceinline__ float edge_m(float f, float s) {
    float sig = __builtin_amdgcn_rcpf(1.0f + __expf(-f));
    float sp  = fmaxf(s, 0.0f) + __logf(1.0f + __expf(-fabsf(s)));
    return sig * sp;
}

// ---------------- embed + BN0 stats fused ----------------
__global__ void embed_stats_kernel(const float* __restrict__ x,
                                   const float* __restrict__ W,   // [12,64]
                                   const float* __restrict__ b,   // [64]
                                   float* __restrict__ out,       // [N,64]
                                   float* __restrict__ stats) {   // [128] pre-zeroed
    int c = threadIdx.x & 63;
    int sub = threadIdx.x >> 6;
    float s = 0.f, q = 0.f;
    for (int r = blockIdx.x * 4 + sub; r < N_NODES; r += gridDim.x * 4) {
        const float* xr = x + r * 12;
        float acc = b[c];
#pragma unroll
        for (int k = 0; k < 12; ++k)
            acc = fmaf(xr[k], W[k * CH + c], acc);
        out[(size_t)r * CH + c] = acc;
        s += acc;
        q = fmaf(acc, acc, q);
    }
    __shared__ float ls[4][64];
    __shared__ float lq[4][64];
    ls[sub][c] = s;
    lq[sub][c] = q;
    __syncthreads();
    if (sub == 0) {
        s = ls[0][c] + ls[1][c] + ls[2][c] + ls[3][c];
        q = lq[0][c] + lq[1][c] + lq[2][c] + lq[3][c];
        atomicAdd(&stats[c], s);
        atomicAdd(&stats[64 + c], q);
    }
}

// ---------------- counting sort of edges by dst ----------------
__global__ void hist_kernel(const int* __restrict__ ei,
                            int* __restrict__ rowptr) { // [N+1] pre-zeroed
    int e = blockIdx.x * blockDim.x + threadIdx.x;
    if (e < N_EDGES) atomicAdd(&rowptr[ei[N_EDGES + e] + 1], 1);
}

__global__ void scanA_kernel(int* __restrict__ a, int* __restrict__ btot) {
    __shared__ int wsum[16];
    int t = threadIdx.x, lane = t & 63, w = t >> 6;
    int i = blockIdx.x * 1024 + t;
    int v = (i <= N_NODES) ? a[i] : 0;
    int s = v;
#pragma unroll
    for (int d = 1; d < 64; d <<= 1) {
        int o = __shfl_up(s, d);
        if (lane >= d) s += o;
    }
    if (lane == 63) wsum[w] = s;
    __syncthreads();
    if (w == 0) {
        int ws2 = (lane < 16) ? wsum[lane] : 0;
#pragma unroll
        for (int d = 1; d < 16; d <<= 1) {
            int o = __shfl_up(ws2, d);
            if (lane >= d) ws2 += o;
        }
        if (lane < 16) wsum[lane] = ws2;
    }
    __syncthreads();
    int off = (w > 0) ? wsum[w - 1] : 0;
    if (i <= N_NODES) a[i] = s + off;
    if (t == 0) btot[blockIdx.x] = wsum[15];
}

__global__ void scanB_kernel(int* __restrict__ btot) { // 1 block, 64 threads
    int lane = threadIdx.x;
    int carry = 0;
    for (int base = 0; base < SCAN_NB; base += 64) {
        int i = base + lane;
        int v = (i < SCAN_NB) ? btot[i] : 0;
        int s = v;
#pragma unroll
        for (int d = 1; d < 64; d <<= 1) {
            int o = __shfl_up(s, d);
            if (lane >= d) s += o;
        }
        if (i < SCAN_NB) btot[i] = s + carry;
        carry += __shfl(s, 63);
    }
}

__global__ void scanC_kernel(int* __restrict__ a, const int* __restrict__ btot,
                             int* __restrict__ cursor) {
    int i = blockIdx.x * 1024 + threadIdx.x;
    int off = (blockIdx.x > 0) ? btot[blockIdx.x - 1] : 0;
    if (i <= N_NODES) {
        int val = a[i] + off;
        a[i] = val;
        if (i < N_NODES) cursor[i] = val;
    }
}

// one 8B random write per edge: sef[pos] = {src, ea_bits}  (measured-best)
__global__ void scatter_kernel(const int* __restrict__ ei,
                               const float* __restrict__ ea,
                               int* __restrict__ cursor,
                               int2* __restrict__ sef) {
    int e = blockIdx.x * blockDim.x + threadIdx.x;
    if (e >= N_EDGES) return;
    int d = ei[N_EDGES + e];
    int pos = atomicAdd(&cursor[d], 1);
    sef[pos] = make_int2(ei[e], __float_as_int(ea[e]));
}

// ---------- weight prep: pqrs layout [P(64) | R(64) | QS interleaved(128)] --
__global__ void prep_weights_kernel(const float* __restrict__ Wf,  // [129,64]
                                    const float* __restrict__ Ws,  // [129,64]
                                    const float* __restrict__ bf,
                                    const float* __restrict__ bs,
                                    _Float16* __restrict__ WT2,    // [256,64]
                                    float* __restrict__ w128,      // [128]
                                    float* __restrict__ bias) {    // [128]
    int idx = blockIdx.x * blockDim.x + threadIdx.x;  // 16384
    if (idx < 256 * 64) {
        int cc = idx >> 6;
        int k = idx & 63;
        float v;
        if (cc < 64)       v = Wf[k * 64 + cc];
        else if (cc < 128) v = Ws[k * 64 + (cc - 64)];
        else {
            int j = cc - 128, ch = j >> 1;
            v = (j & 1) ? Ws[(64 + k) * 64 + ch] : Wf[(64 + k) * 64 + ch];
        }
        WT2[idx] = (_Float16)v;
    }
    if (idx < 128) {
        w128[idx] = (idx < 64) ? Wf[128 * 64 + idx] : Ws[128 * 64 + (idx - 64)];
        bias[idx] = (idx < 64) ? bf[idx] : bs[idx - 64];
    }
}

// ------ node GEMM with fused BN(+res,+relu): h = relu(BN(ain)+res) ---------
template <bool RES>
__global__ __launch_bounds__(256)
void node_gemm_kernel(const float* __restrict__ ain,    // [N,64]
                      const float* __restrict__ res,    // [N,64] or null
                      const float* __restrict__ stats,  // [128]
                      const float* __restrict__ gamma,
                      const float* __restrict__ beta,
                      const _Float16* __restrict__ WT2, // [256,64]
                      float* __restrict__ hout,         // [N,64]
                      _Float16* __restrict__ pqrs) {    // [N,256]
    __shared__ __align__(16) _Float16 As[64 * ZSTRN];
    __shared__ __align__(16) float ab[128];
    const int t = threadIdx.x;
    const int lane = t & 63;
    const int w = t >> 6;
    const int l15 = lane & 15;
    const int quad = lane >> 4;

    if (t < 64) {
        float mean = stats[t] * (1.0f / (float)N_NODES);
        float var  = stats[64 + t] * (1.0f / (float)N_NODES) - mean * mean;
        float inv  = rsqrtf(var + EPS);
        float A = gamma[t] * inv;
        ab[t] = A;
        ab[64 + t] = beta[t] - mean * A;
    }

    half8 bfr[4][2];
#pragma unroll
    for (int tt = 0; tt < 4; ++tt)
#pragma unroll
        for (int ks = 0; ks < 2; ++ks)
            bfr[tt][ks] = *(const half8*)(WT2 + (w * 64 + tt * 16 + l15) * 64 + ks * 32 + quad * 8);
    __syncthreads();

    const int base = blockIdx.x * 64;
    {
        const int e = t >> 2, q = t & 3;
        const int row = base + e;
        const bool valid = (row < N_NODES);
        const int crow = valid ? row : (N_NODES - 1);
        const float* ap = ain + (size_t)crow * CH + q * 16;
        const float* rp = res + (size_t)crow * CH + q * 16;  // unused if !RES
        float vv[16];
#pragma unroll
        for (int i = 0; i < 4; ++i) {
            float4 a4 = *(const float4*)(ap + i * 4);
            float4 A4 = *(const float4*)(ab + q * 16 + i * 4);
            float4 B4 = *(const float4*)(ab + 64 + q * 16 + i * 4);
            float rx = 0.f, ry = 0.f, rz = 0.f, rw = 0.f;
            if (RES) {
                float4 r4 = *(const float4*)(rp + i * 4);
                rx = r4.x; ry = r4.y; rz = r4.z; rw = r4.w;
            }
            vv[i * 4 + 0] = fmaxf(fmaf(a4.x, A4.x, B4.x) + rx, 0.0f);
            vv[i * 4 + 1] = fmaxf(fmaf(a4.y, A4.y, B4.y) + ry, 0.0f);
            vv[i * 4 + 2] = fmaxf(fmaf(a4.z, A4.z, B4.z) + rz, 0.0f);
            vv[i * 4 + 3] = fmaxf(fmaf(a4.w, A4.w, B4.w) + rw, 0.0f);
        }
        if (valid) {
            float* hp = hout + (size_t)row * CH + q * 16;
#pragma unroll
            for (int i = 0; i < 4; ++i)
                *(float4*)(hp + i * 4) = make_float4(vv[i * 4], vv[i * 4 + 1], vv[i * 4 + 2], vv[i * 4 + 3]);
        }
        half8 o;
#pragma unroll
        for (int j = 0; j < 8; ++j) o[j] = (_Float16)vv[j];
        *(half8*)(As + e * ZSTRN + q * 16) = o;
#pragma unroll
        for (int j = 0; j < 8; ++j) o[j] = (_Float16)vv[8 + j];
        *(half8*)(As + e * ZSTRN + q * 16 + 8) = o;
    }
    __syncthreads();

    floatx4 acc[4][4];   // [rt][tt]
#pragma unroll
    for (int rt = 0; rt < 4; ++rt)
#pragma unroll
        for (int tt = 0; tt < 4; ++tt)
#pragma unroll
            for (int r = 0; r < 4; ++r) acc[rt][tt][r] = 0.f;

#pragma unroll
    for (int ks = 0; ks < 2; ++ks) {
#pragma unroll
        for (int rt = 0; rt < 4; ++rt) {
            half8 a = *(const half8*)(As + (rt * 16 + l15) * ZSTRN + ks * 32 + quad * 8);
#pragma unroll
            for (int tt = 0; tt < 4; ++tt)
                acc[rt][tt] = __builtin_amdgcn_mfma_f32_16x16x32_f16(a, bfr[tt][ks], acc[rt][tt], 0, 0, 0);
        }
    }

#pragma unroll
    for (int rt = 0; rt < 4; ++rt) {
#pragma unroll
        for (int r = 0; r < 4; ++r) {
            int row = base + rt * 16 + quad * 4 + r;
            if (row < N_NODES) {
#pragma unroll
                for (int tt = 0; tt < 4; ++tt)
                    pqrs[(size_t)row * 256 + w * 64 + tt * 16 + l15] = (_Float16)acc[rt][tt][r];
            }
        }
    }
}

// --- fused edge compute + aggregation: node walkers, unroll-4 gathers -------
__global__ __launch_bounds__(256)
void edge_agg_kernel(const _Float16* __restrict__ pqrs,  // [N,256] P|R|QS
                     const int2* __restrict__ sef,       // [E] {src, ea}
                     const int* __restrict__ rowptr,     // [N+1]
                     const float* __restrict__ w128,     // [128]
                     const float* __restrict__ bias,     // [128]
                     float* __restrict__ agg,            // [N,64]
                     float* __restrict__ wpart) {        // [NW,128]
    const int lane = threadIdx.x & 63;
    const int gw = (blockIdx.x * blockDim.x + threadIdx.x) >> 6;
    const int nw = NW;
    const float wfc = w128[lane], wsc = w128[64 + lane];
    const float bfc = bias[lane], bsc = bias[64 + lane];
    const char* qsbase = (const char*)pqrs + 256 + (size_t)lane * 4;

    const int e0t = (int)((long)gw * N_EDGES / nw);
    const int e1t = (int)((long)(gw + 1) * N_EDGES / nw);
    int n0 = lbound(rowptr, N_NODES + 1, e0t);
    int n1 = (gw == nw - 1) ? N_NODES : lbound(rowptr, N_NODES + 1, e1t);

    float ssum = 0.f, sqsum = 0.f;
    for (int n = n0; n < n1; ++n) {
        const int rs = rowptr[n], re = rowptr[n + 1];
        const _Float16* prow = pqrs + (size_t)n * 256;
        const float fb = (float)prow[lane] + bfc;
        const float sb = (float)prow[64 + lane] + bsc;
        float acc0 = 0.f, acc1 = 0.f, acc2 = 0.f, acc3 = 0.f;
        int e = rs;
        for (; e + 4 <= re; e += 4) {
            int2 s0 = sef[e];
            int2 s1 = sef[e + 1];
            int2 s2 = sef[e + 2];
            int2 s3 = sef[e + 3];
            half2v q0 = *(const half2v*)(qsbase + ((size_t)s0.x << 9));
            half2v q1 = *(const half2v*)(qsbase + ((size_t)s1.x << 9));
            half2v q2 = *(const half2v*)(qsbase + ((size_t)s2.x << 9));
            half2v q3 = *(const half2v*)(qsbase + ((size_t)s3.x << 9));
            float ea0 = __int_as_float(s0.y), ea1 = __int_as_float(s1.y);
            float ea2 = __int_as_float(s2.y), ea3 = __int_as_float(s3.y);
            acc0 += edge_m(fmaf(ea0, wfc, fb + (float)q0[0]), fmaf(ea0, wsc, sb + (float)q0[1]));
            acc1 += edge_m(fmaf(ea1, wfc, fb + (float)q1[0]), fmaf(ea1, wsc, sb + (float)q1[1]));
            acc2 += edge_m(fmaf(ea2, wfc, fb + (float)q2[0]), fmaf(ea2, wsc, sb + (float)q2[1]));
            acc3 += edge_m(fmaf(ea3, wfc, fb + (float)q3[0]), fmaf(ea3, wsc, sb + (float)q3[1]));
        }
        for (; e < re; ++e) {
            int2 s0 = sef[e];
            half2v q0 = *(const half2v*)(qsbase + ((size_t)s0.x << 9));
            float ea0 = __int_as_float(s0.y);
            acc0 += edge_m(fmaf(ea0, wfc, fb + (float)q0[0]), fmaf(ea0, wsc, sb + (float)q0[1]));
        }
        float acc = (acc0 + acc1) + (acc2 + acc3);
        agg[(size_t)n * CH + lane] = acc;
        ssum += acc;
        sqsum = fmaf(acc, acc, sqsum);
    }
    wpart[(size_t)gw * 128 + lane] = ssum;
    wpart[(size_t)gw * 128 + 64 + lane] = sqsum;
}

// ---- reduce wave partials -> stats[128] (128 blocks x 64 rows each) -------
__global__ __launch_bounds__(256)
void reduce_stats_kernel(const float* __restrict__ wpart, // [NW,128]
                         float* __restrict__ stats) {     // [128] pre-zeroed
    __shared__ float red[2][128];
    const int col = threadIdx.x & 127;
    const int rg = threadIdx.x >> 7;   // 0..1
    const int rows = NW / 128;         // 64
    const int r0 = blockIdx.x * rows;
    float s = 0.f;
    for (int r = r0 + rg; r < r0 + rows; r += 2)
        s += wpart[(size_t)r * 128 + col];
    red[rg][col] = s;
    __syncthreads();
    if (rg == 0) atomicAdd(&stats[col], red[0][col] + red[1][col]);
}

// ---------- pool with fused final BN(+residual): mean over graphs ----------
__global__ __launch_bounds__(256)
void pool_bn_kernel(const float* __restrict__ ain,   // agg3 [N,64]
                    const float* __restrict__ res,   // h2 [N,64]
                    const float* __restrict__ stats, // [128]
                    const float* __restrict__ gamma,
                    const float* __restrict__ beta,
                    const int* __restrict__ batch,
                    float* __restrict__ pooled,      // [G,64] pre-zeroed
                    float* __restrict__ counts) {    // [G]   pre-zeroed
    __shared__ float ab[128];
    if (threadIdx.x < 64) {
        int t = threadIdx.x;
        float mean = stats[t] * (1.0f / (float)N_NODES);
        float var  = stats[64 + t] * (1.0f / (float)N_NODES) - mean * mean;
        float inv  = rsqrtf(var + EPS);
        float A = gamma[t] * inv;
        ab[t] = A;
        ab[64 + t] = beta[t] - mean * A;
    }
    __syncthreads();

    const int c = threadIdx.x & 63;
    const float A = ab[c], B = ab[64 + c];
    const int walker = blockIdx.x * 4 + (threadIdx.x >> 6);
    const int nwalk = POOL_BLOCKS * 4;
    const int chunk = (N_NODES + nwalk - 1) / nwalk;
    int r0 = walker * chunk;
    int r1 = min(N_NODES, r0 + chunk);
    if (r0 >= r1) return;

    int cur = batch[r0];
    float acc = 0.0f;
    int runlen = 0;
    for (int r = r0; r < r1; ++r) {
        int b = batch[r];
        if (b != cur) {
            atomicAdd(&pooled[cur * CH + c], acc);
            if (c == 0) atomicAdd(&counts[cur], (float)runlen);
            acc = 0.0f;
            runlen = 0;
            cur = b;
        }
        size_t idx = (size_t)r * CH + c;
        acc += fmaf(ain[idx], A, B) + res[idx];
        ++runlen;
    }
    atomicAdd(&pooled[cur * CH + c], acc);
    if (c == 0) atomicAdd(&counts[cur], (float)runlen);
}

// ---------------- head ----------------
__global__ void head_kernel(const float* __restrict__ pooled,
                            const float* __restrict__ counts,
                            const float* __restrict__ W1,
                            const float* __restrict__ b1,
                            const float* __restrict__ W2,
                            const float* __restrict__ b2,
                            float* __restrict__ out) {
    int gph = blockIdx.x;
    int t = threadIdx.x;  // 64
    __shared__ float p[64];
    __shared__ float h1[32];
    float cnt = fmaxf(counts[gph], 1.0f);
    p[t] = pooled[gph * CH + t] / cnt;
    __syncthreads();
    if (t < 32) {
        float acc = b1[t];
#pragma unroll
        for (int c = 0; c < 64; ++c)
            acc = fmaf(p[c], W1[c * 32 + t], acc);
        h1[t] = fmaxf(acc, 0.0f);
    }
    __syncthreads();
    if (t == 0) {
        float acc = b2[0];
#pragma unroll
        for (int j = 0; j < 32; ++j)
            acc = fmaf(h1[j], W2[j], acc);
        out[gph] = acc;
    }
}

extern "C" void kernel_launch(void* const* d_in, const int* in_sizes, int n_in,
                              void* d_out, int out_size, void* d_ws, size_t ws_size,
                              hipStream_t stream) {
    const float* x     = (const float*)d_in[0];
    const int*   ei    = (const int*)d_in[1];
    const float* ea    = (const float*)d_in[2];
    const int*   batch = (const int*)d_in[3];
    const float* W_in  = (const float*)d_in[4];
    const float* b_in  = (const float*)d_in[5];
    const float* g0    = (const float*)d_in[6];
    const float* beta0 = (const float*)d_in[7];

    const float* Wf[3] = {(const float*)d_in[8],  (const float*)d_in[14], (const float*)d_in[20]};
    const float* bfv[3]= {(const float*)d_in[9],  (const float*)d_in[15], (const float*)d_in[21]};
    const float* Wsv[3]= {(const float*)d_in[10], (const float*)d_in[16], (const float*)d_in[22]};
    const float* bsv[3]= {(const float*)d_in[11], (const float*)d_in[17], (const float*)d_in[23]};
    const float* gm[3] = {(const float*)d_in[12], (const float*)d_in[18], (const float*)d_in[24]};
    const float* bb[3] = {(const float*)d_in[13], (const float*)d_in[19], (const float*)d_in[25]};

    const float* W1 = (const float*)d_in[26];
    const float* b1 = (const float*)d_in[27];
    const float* W2 = (const float*)d_in[28];
    const float* b2 = (const float*)d_in[29];

    float* out = (float*)d_out;

    // ---- workspace layout (byte-based) ----
    char* base = (char*)d_ws;
    size_t off = 0;
    float* bufA = (float*)(base + off);       off += (size_t)NC * 4;  // E0 / h1
    float* bufB = (float*)(base + off);       off += (size_t)NC * 4;  // h0 / h2
    float* AGG  = (float*)(base + off);       off += (size_t)NC * 4;
    _Float16* WT2 = (_Float16*)(base + off);  off += 3 * 256 * 64 * 2;
    float* w128   = (float*)(base + off);     off += 3 * 128 * 4;
    float* biasL  = (float*)(base + off);     off += 3 * 128 * 4;
    int* cursor   = (int*)(base + off);       off += (size_t)N_NODES * 4;
    int2* sef     = (int2*)(base + off);      off += (size_t)N_EDGES * 8;
    _Float16* pqrs = (_Float16*)(base + off); off += (size_t)N_NODES * 256 * 2; // 51.2MB
    float* wpart  = (float*)(base + off);     off += (size_t)NW * 128 * 4;      // 4MB
    // ---- contiguous zero-region ----
    char* zbase   = base + off;
    int* rowptr   = (int*)(base + off);       off += (size_t)(N_NODES + 1) * 4;
    int* btot     = (int*)(base + off);       off += SCAN_NB * 4;
    float* stats4 = (float*)(base + off);     off += 4 * 128 * 4;   // stats l=0..3
    float* pooled = (float*)(base + off);     off += (size_t)N_GRAPHS * CH * 4;
    float* counts = (float*)(base + off);     off += (size_t)N_GRAPHS * 4;
    size_t zbytes = (size_t)(base + off - zbase);

    const int edgeBlocks = (N_EDGES + 255) / 256;

    hipMemsetAsync(zbase, 0, zbytes, stream);

    // ---- sort edges by dst: hist + 3-phase scan + direct sef scatter ----
    hist_kernel<<<edgeBlocks, 256, 0, stream>>>(ei, rowptr);
    scanA_kernel<<<SCAN_NB, 1024, 0, stream>>>(rowptr, btot);
    scanB_kernel<<<1, 64, 0, stream>>>(btot);
    scanC_kernel<<<SCAN_NB, 1024, 0, stream>>>(rowptr, btot, cursor);
    scatter_kernel<<<edgeBlocks, 256, 0, stream>>>(ei, ea, cursor, sef);

    // ---- prep f16 weights (P|R|QS-interleaved column order) ----
    for (int l = 0; l < 3; ++l)
        prep_weights_kernel<<<64, 256, 0, stream>>>(Wf[l], Wsv[l], bfv[l], bsv[l],
                                                    WT2 + l * 256 * 64, w128 + l * 128,
                                                    biasL + l * 128);

    // ---- embed + BN0 stats ----
    embed_stats_kernel<<<512, 256, 0, stream>>>(x, W_in, b_in, bufA, stats4);

    // ---- layer pipeline ----
    node_gemm_kernel<false><<<GTILES, 256, 0, stream>>>(
        bufA, nullptr, stats4, g0, beta0, WT2 + 0 * 256 * 64, bufB, pqrs);
    edge_agg_kernel<<<EA_BLOCKS, 256, 0, stream>>>(
        pqrs, sef, rowptr, w128 + 0 * 128, biasL + 0 * 128, AGG, wpart);
    reduce_stats_kernel<<<128, 256, 0, stream>>>(wpart, stats4 + 128);

    node_gemm_kernel<true><<<GTILES, 256, 0, stream>>>(
        AGG, bufB, stats4 + 128, gm[0], bb[0], WT2 + 1 * 256 * 64, bufA, pqrs);
    edge_agg_kernel<<<EA_BLOCKS, 256, 0, stream>>>(
        pqrs, sef, rowptr, w128 + 1 * 128, biasL + 1 * 128, AGG, wpart);
    reduce_stats_kernel<<<128, 256, 0, stream>>>(wpart, stats4 + 256);

    node_gemm_kernel<true><<<GTILES, 256, 0, stream>>>(
        AGG, bufA, stats4 + 256, gm[1], bb[1], WT2 + 2 * 256 * 64, bufB, pqrs);
    edge_agg_kernel<<<EA_BLOCKS, 256, 0, stream>>>(
        pqrs, sef, rowptr, w128 + 2 * 128, biasL + 2 * 128, AGG, wpart);
    reduce_stats_kernel<<<128, 256, 0, stream>>>(wpart, stats4 + 384);

    // pool with fused BN3 + residual h2
    pool_bn_kernel<<<POOL_BLOCKS, 256, 0, stream>>>(
        AGG, bufB, stats4 + 384, gm[2], bb[2], batch, pooled, counts);
    head_kernel<<<N_GRAPHS, 64, 0, stream>>>(pooled, counts, W1, b1, W2, b2, out);
}